// Round 11
// baseline (1417.205 us; speedup 1.0000x reference)
//
#include <hip/hip_runtime.h>
#include <hip/hip_bf16.h>

typedef __hip_bfloat16 bf16;
typedef unsigned short ushortT;
typedef __attribute__((ext_vector_type(8))) short short8;
typedef __attribute__((ext_vector_type(4))) short s16x4;
typedef __attribute__((ext_vector_type(4))) float f32x4;

#define BB 128
#define CHAN 24
#define INNER 64
#define HW 1024
#define DD (CHAN*HW)              // 24576

constexpr size_t cBD = (size_t)BB*DD;        // 3145728 elems
constexpr size_t cYB = (size_t)BB*INNER*HW;  // 8388608 elems

// ---------------- scratch in device globals ----------------
// aidx chunked bf16: [b][icv(3)][pix(1024)][8]  (c = icv*8+e)
__device__ __attribute__((aligned(16))) ushortT g_xp[cBD];   // tidx fragment layout
__device__ __attribute__((aligned(16))) ushortT g_X[5*cBD];
__device__ __attribute__((aligned(16))) ushortT g_F[5*cBD];
__device__ __attribute__((aligned(16))) ushortT g_G[5*cBD];
__device__ __attribute__((aligned(16))) ushortT g_yb[cYB];   // [b][pix][64]
__device__ __attribute__((aligned(16))) ushortT g_tb[cBD];   // preconv staging only
__device__ __attribute__((aligned(16))) ushortT g_w1m[9*64*32]; // bf16 [s][oc64][icp32]
__device__ __attribute__((aligned(16))) ushortT g_w2m[9*24*64]; // bf16 [s][oc24][ic64]
__device__ __attribute__((aligned(16))) float g_stats2a[48];
__device__ __attribute__((aligned(16))) float g_stats2b[48];
__device__ __attribute__((aligned(16))) float g_gn1sum[BB*8*2];
__device__ __attribute__((aligned(16))) float g_gram[BB*25];
__device__ __attribute__((aligned(16))) float g_params[5120];
__device__ unsigned g_isbf16;

#define P_PCW 0
#define P_PCB 648
#define P_PBG 672
#define P_PBB 696
#define P_G1G 720
#define P_G1B 784
#define P_G2G 848
#define P_G2B 872
#define P_G3G 896
#define P_G3B 920
#define P_POG 944
#define P_POB 968
#define P_FCW 992
#define P_FCB 4832

__device__ __forceinline__ size_t aidx(int b, int icv, int pix){
  return (((size_t)b*3 + icv)*1024 + (size_t)pix)*8;
}
// tiled-fragment index: element (b, c, pix) with pix = g*16+p
__device__ __forceinline__ size_t tidx(int b, int g, int c, int p){
  return ((((size_t)b*64 + g)*24 + c)<<4) + p;
}
__device__ __forceinline__ float rdin(const void* p, int i){
  if (g_isbf16) return __bfloat162float(((const bf16*)p)[i]);
  return ((const float*)p)[i];
}
__device__ __forceinline__ float b2f(ushortT u){
  unsigned v = ((unsigned)u) << 16;
  return __builtin_bit_cast(float, v);
}
__device__ __forceinline__ ushortT f2b(float f){
  unsigned u = __builtin_bit_cast(unsigned, f);
  u += 0x7FFFu + ((u >> 16) & 1u);   // RNE
  return (ushortT)(u >> 16);
}
__device__ __forceinline__ void ld24c(const ushortT* base, int b, int pix, float* o){
  #pragma unroll
  for (int icv=0;icv<3;icv++){
    short8 v = *(const short8*)&base[aidx(b,icv,pix)];
    #pragma unroll
    for (int j=0;j<8;j++) o[icv*8+j] = b2f((ushortT)v[j]);
  }
}
__device__ __forceinline__ void st24c(ushortT* base, int b, int pix, const float* i){
  #pragma unroll
  for (int icv=0;icv<3;icv++){
    short8 v;
    #pragma unroll
    for (int j=0;j<8;j++) v[j] = (short)f2b(i[icv*8+j]);
    *(short8*)&base[aidx(b,icv,pix)] = v;
  }
}

// ---- dtype detector ----
__global__ void detect_k(const void* g1g){
  if (threadIdx.x==0 && blockIdx.x==0){
    unsigned u = *(const unsigned*)g1g;
    g_isbf16 = (u == 0x3F803F80u) ? 1u : 0u;
  }
}

// ---- convert params to fp32; zero BN sum buffers ----
__global__ void cvt_params_k(const void* pcw, const void* pcb, const void* pbg, const void* pbb,
                             const void* g1g, const void* g1b, const void* g2g, const void* g2b,
                             const void* g3g, const void* g3b, const void* pog, const void* pob,
                             const void* fcw, const void* fcb){
  int t = threadIdx.x;
  for (int i=t;i<648;i+=256)  g_params[P_PCW+i]=rdin(pcw,i);
  for (int i=t;i<24;i+=256) { g_params[P_PCB+i]=rdin(pcb,i);
                              g_params[P_PBG+i]=rdin(pbg,i);
                              g_params[P_PBB+i]=rdin(pbb,i);
                              g_params[P_G2G+i]=rdin(g2g,i);
                              g_params[P_G2B+i]=rdin(g2b,i);
                              g_params[P_G3G+i]=rdin(g3g,i);
                              g_params[P_G3B+i]=rdin(g3b,i);
                              g_params[P_POG+i]=rdin(pog,i);
                              g_params[P_POB+i]=rdin(pob,i); }
  for (int i=t;i<64;i+=256) { g_params[P_G1G+i]=rdin(g1g,i);
                              g_params[P_G1B+i]=rdin(g1b,i); }
  for (int i=t;i<3840;i+=256) g_params[P_FCW+i]=rdin(fcw,i);
  for (int i=t;i<10;i+=256)   g_params[P_FCB+i]=rdin(fcb,i);
  for (int i=t;i<48;i+=256) { g_stats2a[i]=0.f; g_stats2b[i]=0.f; }
}

// ---- weight pack to bf16 MFMA layouts ----
__global__ void wtm_k(const void* w1, const void* w2){
  int t = blockIdx.x*256 + threadIdx.x;
  if (t < 9*64*32){
    int ic = t & 31, oc = (t>>5)&63, s9 = t>>11;
    float v = (ic<24) ? rdin(w1, (oc*24+ic)*9 + s9) : 0.f;
    g_w1m[t] = f2b(v);
  }
  int u = t - 9*64*32;
  if (u >= 0 && u < 9*24*64){
    int ic = u & 63; int rest = u >> 6; int oc = rest % 24; int s9 = rest / 24;
    g_w2m[u] = f2b(rdin(w2, (oc*64+ic)*9 + s9));
  }
}

// grid 4096: zero yb, X0, gn1sum
__global__ void zero0_k(){
  size_t base = ((size_t)blockIdx.x*256 + threadIdx.x)*8;
  short8 z = {0,0,0,0,0,0,0,0};
  *(short8*)&g_yb[base] = z;
  if (blockIdx.x < 1536) *(short8*)&g_X[base] = z;
  int t = blockIdx.x*256 + threadIdx.x;
  if (blockIdx.x < 8)  g_gn1sum[t] = 0.f;
}

// ---- pre conv -> g_tb (aidx) + pre-BN stats (fused) ----
__global__ void preconv_k(const void* __restrict__ x){
  __shared__ float sR2d[4*48];
  int id = blockIdx.x*256 + threadIdx.x;   // pixel id 0..131071
  int b = id >> 10, pix = id & 1023;
  int yy = pix >> 5, xx = pix & 31;
  float acc[24];
  #pragma unroll
  for (int oc=0;oc<24;oc++) acc[oc] = g_params[P_PCB+oc];
  for (int ic=0; ic<3; ic++)
    for (int ky=0; ky<3; ky++){
      int gy = yy+ky-1; if (gy<0||gy>=32) continue;
      for (int kx=0;kx<3;kx++){
        int gx = xx+kx-1; if (gx<0||gx>=32) continue;
        float v = rdin(x, ((b*3+ic)*32+gy)*32+gx);
        #pragma unroll
        for (int oc=0;oc<24;oc++)
          acc[oc] += v * g_params[P_PCW+(oc*3+ic)*9+ky*3+kx];
      }
    }
  st24c(g_tb, b, pix, acc);
  int lane = threadIdx.x & 63, wv = threadIdx.x >> 6;
  #pragma unroll
  for (int c=0;c<24;c++){
    float r = acc[c], q = acc[c]*acc[c];
    #pragma unroll
    for (int off=32;off;off>>=1){ r += __shfl_down(r,off,64); q += __shfl_down(q,off,64); }
    if (lane==0){ sR2d[wv*48+c*2]=r; sR2d[wv*48+c*2+1]=q; }
  }
  __syncthreads();
  if (threadIdx.x < 48)
    atomicAdd(&g_stats2a[threadIdx.x],
      sR2d[threadIdx.x] + sR2d[48+threadIdx.x] + sR2d[96+threadIdx.x] + sR2d[144+threadIdx.x]);
}

// ---- bn apply: tb (aidx) -> xp (tidx fragment layout) ----
__global__ void bn_apply_k(){
  int id = blockIdx.x*256+threadIdx.x;   // pixel
  int b = id >> 10, pix = id & 1023;
  const float inv = 1.f/(BB*HW);
  float tv[24];
  ld24c(g_tb, b, pix, tv);
  int g = pix >> 4, p = pix & 15;
  #pragma unroll
  for (int c=0;c<24;c++){
    float mean = g_stats2a[c*2]*inv;
    float var = fmaxf(g_stats2a[c*2+1]*inv - mean*mean, 0.f);
    float rstd = rsqrtf(var + 1e-5f);
    float ov = (tv[c]-mean)*rstd*g_params[P_PBG+c] + g_params[P_PBB+c];
    g_xp[tidx(b,g,c,p)] = f2b(ov);
  }
}

// ============ conv1 MFMA (r10 verbatim, XCD-aligned block decode): X[s] -> yb + GN1 ============
__launch_bounds__(256, 2)
__global__ void conv1_k(int s){
  __shared__ ushortT sMem[29312];   // sA 10880 | sW 18432 ; reused as sOut(16384)
  ushortT* sA = sMem;
  ushortT* sW = sMem + 10880;
  const int tid = threadIdx.x;
  const int lane = tid & 63, wv = tid >> 6;
  const int mLane = lane & 15, q = lane >> 4;
  const int bid = blockIdx.x;
  const int b = (bid & 7) + ((bid >> 5) << 3);
  const int yt = (bid >> 3) & 3;
  const ushortT* __restrict__ Xs = g_X + (size_t)s*cBD;
  for (int i = tid; i < 1360; i += 256){
    int icv = i & 3, apix = i >> 2;
    int yl = apix / 34, xl = apix - yl*34;
    int gy = yt*8 - 1 + yl, gx = xl - 1;
    short8 v = {0,0,0,0,0,0,0,0};
    if (gy >= 0 && gy < 32 && gx >= 0 && gx < 32 && icv < 3)
      v = *(const short8*)&Xs[aidx(b, icv, gy*32 + gx)];
    *(short8*)&sA[(size_t)(apix*4 + (icv ^ (apix&3)))*8] = v;
  }
  for (int i = tid; i < 2304; i += 256){
    int icv = i & 3, rest = i >> 2;
    int oc = rest & 63, s9 = rest >> 6;
    short8 v = *(const short8*)&g_w1m[(size_t)((s9*64 + oc)*32) + icv*8];
    *(short8*)&sW[(size_t)((s9*64+oc)*4 + (icv ^ (oc&3)))*8] = v;
  }
  __syncthreads();
  f32x4 acc[4][4];
  #pragma unroll
  for (int mt=0;mt<4;mt++)
    #pragma unroll
    for (int nt=0;nt<4;nt++) acc[mt][nt] = (f32x4){0.f,0.f,0.f,0.f};
  for (int s9=0; s9<9; s9++){
    int ky = s9/3, kx = s9 - ky*3;
    short8 bfr[4];
    #pragma unroll
    for (int nt=0;nt<4;nt++){
      int oc = nt*16 + mLane;
      bfr[nt] = *(const short8*)&sW[(size_t)((s9*64+oc)*4 + (q ^ (oc&3)))*8];
    }
    #pragma unroll
    for (int mt=0;mt<4;mt++){
      int g = wv*4+mt;
      int apix = ((g>>1) + ky)*34 + (g&1)*16 + mLane + kx;
      short8 afr = *(const short8*)&sA[(size_t)(apix*4 + (q ^ (apix&3)))*8];
      #pragma unroll
      for (int nt=0;nt<4;nt++)
        acc[mt][nt] = __builtin_amdgcn_mfma_f32_16x16x32_bf16(afr, bfr[nt], acc[mt][nt], 0,0,0);
    }
  }
  __syncthreads();
  ushortT* sOut = sMem;
  #pragma unroll
  for (int mt=0;mt<4;mt++){
    int g = wv*4+mt;
    #pragma unroll
    for (int nt=0;nt<4;nt++){
      int oc = nt*16 + mLane;
      #pragma unroll
      for (int r=0;r<4;r++){
        int pix = (g>>1)*32 + (g&1)*16 + q*4 + r;
        sOut[pix*64 + oc] = f2b(fmaxf(acc[mt][nt][r], 0.f));
      }
    }
  }
  __syncthreads();
  float s0=0.f, s1=0.f;
  size_t gbase = ((size_t)b*1024 + yt*256)*64;
  for (int c = tid; c < 2048; c += 256){
    short8 v = *(const short8*)&sOut[c*8];
    *(short8*)&g_yb[gbase + (size_t)c*8] = v;
    #pragma unroll
    for (int j=0;j<8;j++){ float f = b2f((ushortT)v[j]); s0 += f; s1 += f*f; }
  }
  s0 += __shfl_down(s0,32); s1 += __shfl_down(s1,32);
  s0 += __shfl_down(s0,16); s1 += __shfl_down(s1,16);
  s0 += __shfl_down(s0, 8); s1 += __shfl_down(s1, 8);
  if (lane < 8){
    atomicAdd(&g_gn1sum[(b*8+lane)*2],   s0);
    atomicAdd(&g_gn1sum[(b*8+lane)*2+1], s1);
  }
}

// ---- Cholesky solve for Anderson alpha ----
template<int N>
__device__ __forceinline__ void chol_alpha(const float Kf[5][5], float* alpha){
  double K[N][N];
  #pragma unroll
  for (int i=0;i<N;i++)
    #pragma unroll
    for (int j=0;j<N;j++)
      K[i][j] = (double)Kf[i][j] + (i==j ? 1e-4 : 0.0);
  #pragma unroll
  for (int c=0;c<N;c++){
    double d = K[c][c];
    #pragma unroll
    for (int k2=0;k2<c;k2++) d -= K[c][k2]*K[c][k2];
    d = sqrt(fmax(d, 1e-300));
    K[c][c] = d;
    double inv = 1.0/d;
    #pragma unroll
    for (int r=c+1;r<N;r++){
      double v = K[r][c];
      #pragma unroll
      for (int k2=0;k2<c;k2++) v -= K[r][k2]*K[c][k2];
      K[r][c] = v*inv;
    }
  }
  double y[N];
  #pragma unroll
  for (int i=0;i<N;i++){
    double v = 1.0;
    #pragma unroll
    for (int j=0;j<i;j++) v -= K[i][j]*y[j];
    y[i] = v / K[i][i];
  }
  double w[N];
  #pragma unroll
  for (int i=N-1;i>=0;i--){
    double v = y[i];
    #pragma unroll
    for (int j=i+1;j<N;j++) v -= K[j][i]*w[j];
    w[i] = v / K[i][i];
  }
  double sum = 0.0;
  #pragma unroll
  for (int i=0;i<N;i++) sum += w[i];
  double invs = 1.0/sum;
  #pragma unroll
  for (int i=0;i<N;i++) alpha[i] = (float)(w[i]*invs);
}

// ====== c2f_k: conv2 (whole image, MFMA) + fuse, one block/batch ======
// 128 blocks x 1024 threads. LDS (ushort offsets):
//   [0,65536)      sYb: [pix][8 slot=chk^(pix&7)][8]   (128 KB)
//                  sTB alias after conv2: [pix][4 slot=icv^((pix>>2)&3)][8] (64 KB)
//   [65536,79360)  sW2: [s9][oc][8 slot=icv^(oc&7)][8] (27 KB)
//   floats after:  680 floats
#define C2F_SMEM 161440

__launch_bounds__(1024)
__global__ void c2f_k(int s, int n, int snext){
  extern __shared__ __align__(16) ushortT sU[];
  ushortT* sYb = sU;
  ushortT* sTB = sU;
  ushortT* sW2 = sU + 65536;
  float* sS    = (float*)(sU + 79360);
  float* sAff1  = sS;         // 128
  float* sStat2 = sS + 128;   // 48
  float* sAff2  = sS + 176;   // 48
  float* sAff3  = sS + 240;   // 48
  float* sRed   = sS + 288;   // 256 (16 waves x 8grp x {S,Q})
  float* sRedG  = sS + 544;   // 80
  float* sAlpha = sS + 624;   // 8
  float* sFin   = (float*)sTB; // fin-only scratch (region dead by then)

  const int b = blockIdx.x;
  const int t = threadIdx.x;
  const int lane = t & 63, wv = t >> 6;
  const int mLane = lane & 15, q = lane >> 4;
  const int g0 = wv*4;
  const bool ntOK = (mLane < 8);
  const bool fin = (n == 0);

  // GN1 affine from conv1's global sums, then zero them for next iter
  if (t < 64){
    const int c = t, gr = c>>3;
    float S = g_gn1sum[(b*8+gr)*2], Q = g_gn1sum[(b*8+gr)*2+1];
    float mean = S*(1.f/8192.f);
    float var  = fmaxf(Q*(1.f/8192.f) - mean*mean, 0.f);
    float rstd = rsqrtf(var + 1e-5f);
    float sc = rstd*g_params[P_G1G+c];
    sAff1[c] = sc; sAff1[64+c] = g_params[P_G1B+c] - mean*sc;
  }
  if (t < 16) g_gn1sum[b*16 + t] = 0.f;   // same wave, after reads
  if (t >= 64 && t < 112) sStat2[t-64] = 0.f;
  __syncthreads();   // (A) sAff1 ready

  // stage yb (GN1 applied, bf16-rounded) + w2 into swizzled LDS
  for (int i=t; i<8192; i+=1024){
    int chk = i & 7, pix = i >> 3;
    short8 raw = *(const short8*)&g_yb[((size_t)b*1024 + pix)*64 + chk*8];
    short8 v;
    #pragma unroll
    for (int j=0;j<8;j++){
      int c = chk*8+j;
      v[j] = (short)f2b(b2f((ushortT)raw[j])*sAff1[c] + sAff1[64+c]);
    }
    *(short8*)&sYb[(size_t)(pix*8 + (chk^(pix&7)))*8] = v;
  }
  for (int i=t; i<1728; i+=1024){
    int icv=i&7, rest=i>>3, oc=rest%24, s9=rest/24;
    *(short8*)&sW2[(size_t)((s9*24+oc)*8 + (icv^(oc&7)))*8] =
      *(const short8*)&g_w2m[(size_t)((s9*24+oc)*64) + icv*8];
  }
  __syncthreads();   // (B) yb, w2 ready

  // prefetch xp fragments (8B vector loads) -- latency hides under the MFMA loop
  s16x4 xpv[2][4];
  #pragma unroll
  for (int ci=0; ci<2; ++ci)
    #pragma unroll
    for (int mt=0; mt<4; ++mt){
      const int oc = ci*16 + mLane;
      if (ci==0 || ntOK)
        xpv[ci][mt] = *(const s16x4*)&g_xp[tidx(b, g0+mt, oc, q*4)];
      else
        xpv[ci][mt] = (s16x4){0,0,0,0};
    }

  // ---------------- conv2 MFMA: whole image, wave -> 64 pixels ----------------
  f32x4 a2[4][2];
  #pragma unroll
  for (int mt=0;mt<4;mt++){ a2[mt][0]=(f32x4){0.f,0.f,0.f,0.f}; a2[mt][1]=(f32x4){0.f,0.f,0.f,0.f}; }
  for (int s9=0; s9<9; ++s9){
    const int ky = s9/3, kx = s9 - ky*3;
    #pragma unroll
    for (int ks=0; ks<2; ++ks){
      const int ch = ks*4 + q;
      short8 b0 = *(const short8*)&sW2[(size_t)((s9*24+mLane)*8 + (ch^(mLane&7)))*8];
      short8 b1 = ntOK ? *(const short8*)&sW2[(size_t)((s9*24+16+mLane)*8 + (ch^(mLane&7)))*8]
                       : (short8){0,0,0,0,0,0,0,0};
      #pragma unroll
      for (int mt=0;mt<4;mt++){
        const int g = g0+mt;
        const int gy = (g>>1) + ky - 1;
        const int gx = (g&1)*16 + mLane + kx - 1;
        short8 afr = {0,0,0,0,0,0,0,0};
        if (gy>=0 && gy<32 && gx>=0 && gx<32){
          const int pp = gy*32 + gx;
          afr = *(const short8*)&sYb[(size_t)(pp*8 + (ch^(pp&7)))*8];
        }
        a2[mt][0] = __builtin_amdgcn_mfma_f32_16x16x32_bf16(afr, b0, a2[mt][0], 0,0,0);
        a2[mt][1] = __builtin_amdgcn_mfma_f32_16x16x32_bf16(afr, b1, a2[mt][1], 0,0,0);
      }
    }
  }
  // v = a2 + xp (prefetched) ; GN2 stats (unrounded)
  #pragma unroll
  for (int ci=0; ci<2; ++ci){
    const int oc = ci*16 + mLane;
    const bool ok = (ci==0) || ntOK;
    float s0=0.f, s1=0.f;
    if (ok){
      #pragma unroll
      for (int mt=0;mt<4;mt++){
        #pragma unroll
        for (int r=0;r<4;r++){
          float v = a2[mt][ci][r] + b2f((ushortT)xpv[ci][mt][r]);
          a2[mt][ci][r] = v;
          s0 += v; s1 += v*v;
        }
      }
    }
    s0 += __shfl_down(s0,32); s1 += __shfl_down(s1,32);
    s0 += __shfl_down(s0,16); s1 += __shfl_down(s1,16);
    if (lane < 16 && ok){
      atomicAdd(&sStat2[oc*2],   s0);
      atomicAdd(&sStat2[oc*2+1], s1);
    }
  }
  __syncthreads();   // (C) all sYb reads + stats2 done -> region reusable

  // prefetch own-pixel X[s] (used after (D); c2f only writes X[snext], snext != s)
  short8 xv8[3];
  #pragma unroll
  for (int i=0;i<3;i++)
    xv8[i] = *(const short8*)&g_X[(size_t)s*cBD + aidx(b,i,t)];

  // handoff tb' = f2b(v) into sTB (dead yb region)
  #pragma unroll
  for (int ci=0; ci<2; ++ci){
    const int oc = ci*16 + mLane;
    if ((ci==0) || ntOK){
      const int icv = oc>>3, e = oc&7;
      #pragma unroll
      for (int mt=0;mt<4;mt++)
        #pragma unroll
        for (int r=0;r<4;r++){
          const int pp = (g0+mt)*16 + q*4 + r;
          sTB[(size_t)(pp*4 + (icv ^ ((pp>>2)&3)))*8 + e] = f2b(a2[mt][ci][r]);
        }
    }
  }
  if (t < 24){
    const int gr = t/3;
    float S = sStat2[(gr*3)*2]  +sStat2[(gr*3+1)*2]  +sStat2[(gr*3+2)*2];
    float Q = sStat2[(gr*3)*2+1]+sStat2[(gr*3+1)*2+1]+sStat2[(gr*3+2)*2+1];
    float m = S*(1.f/3072.f);
    float rstd = rsqrtf(fmaxf(Q*(1.f/3072.f)-m*m,0.f)+1e-5f);
    float sc = rstd*g_params[P_G2G+t];
    sAff2[t] = sc; sAff2[24+t] = g_params[P_G2B+t] - m*sc;
  }
  __syncthreads();   // (D) handoff + aff2 ready

  // ---------------- pixel phase (t = pixel) ----------------
  float v[24], xv[24];
  #pragma unroll
  for (int i=0;i<3;i++){
    short8 t8 = *(const short8*)&sTB[(size_t)(t*4 + (i ^ ((t>>2)&3)))*8];
    #pragma unroll
    for (int j8=0;j8<8;j8++){
      v[i*8+j8]  = b2f((ushortT)t8[j8]);
      xv[i*8+j8] = b2f((ushortT)xv8[i][j8]);
    }
  }
  float p0[8], p1[8];
  #pragma unroll
  for (int g=0;g<8;g++){ p0[g]=0.f; p1[g]=0.f; }
  #pragma unroll
  for (int c=0;c<24;c++){
    float val = fmaxf(xv[c] + v[c]*sAff2[c] + sAff2[24+c], 0.f);
    v[c] = val;
    int g = c/3;
    p0[g] += val; p1[g] += val*val;
  }
  #pragma unroll
  for (int g=0;g<8;g++){
    #pragma unroll
    for (int off=32;off;off>>=1){ p0[g]+=__shfl_down(p0[g],off,64); p1[g]+=__shfl_down(p1[g],off,64); }
  }
  if (lane==0){
    #pragma unroll
    for (int g=0;g<8;g++){ sRed[wv*16+g*2]=p0[g]; sRed[wv*16+g*2+1]=p1[g]; }
  }
  __syncthreads();   // (E) -- sTB reads also all done
  // merged GN3 reduce + affine (was two phases)
  if (t < 24){
    const int g = t/3;
    float S=0.f, Q=0.f;
    #pragma unroll
    for (int w=0;w<16;w++){ S += sRed[w*16+g*2]; Q += sRed[w*16+g*2+1]; }
    float m = S*(1.f/3072.f);
    float rstd = rsqrtf(fmaxf(Q*(1.f/3072.f) - m*m, 0.f) + 1e-5f);
    float sc = rstd*g_params[P_G3G+t];
    sAff3[t] = sc; sAff3[24+t] = g_params[P_G3B+t] - m*sc;
  }
  __syncthreads();   // (F')
  float fv[24];
  #pragma unroll
  for (int c=0;c<24;c++) fv[c] = v[c]*sAff3[c] + sAff3[24+c];
  st24c(g_F + (size_t)s*cBD, b, t, fv);

  if (!fin){
    float gl[24];
    #pragma unroll
    for (int c=0;c<24;c++) gl[c] = b2f(f2b(fv[c] - xv[c]));   // bf16-rounded residual
    st24c(g_G + (size_t)s*cBD, b, t, gl);
    float part[5];
    #pragma unroll
    for (int j=0;j<5;j++) part[j]=0.f;
    #pragma unroll
    for (int j=0;j<5;j++){
      if (j < n){
        float acc=0.f;
        if (j == s){
          #pragma unroll
          for (int c=0;c<24;c++) acc += gl[c]*gl[c];
        } else {
          float gv[24];
          ld24c(g_G + (size_t)j*cBD, b, t, gv);
          #pragma unroll
          for (int c=0;c<24;c++) acc += gl[c]*gv[c];
        }
        part[j] = acc;
      }
    }
    #pragma unroll
    for (int j=0;j<5;j++){
      float vv = part[j];
      #pragma unroll
      for (int off=32;off;off>>=1) vv += __shfl_down(vv,off,64);
      if (lane==0) sRedG[wv*5+j] = vv;
    }
    __syncthreads();   // (H)
    if (t == 0){
      for (int j=0;j<n;j++){
        float vv = 0.f;
        for (int w=0;w<16;w++) vv += sRedG[w*5+j];
        g_gram[b*25+s*5+j] = vv;
        g_gram[b*25+j*5+s] = vv;
      }
      float Kf[5][5];
      for (int i=0;i<n;i++)
        for (int j=0;j<n;j++) Kf[i][j] = g_gram[b*25+i*5+j];
      float al[5];
      if (n==1) al[0]=1.f;
      else if (n==2) chol_alpha<2>(Kf, al);
      else if (n==3) chol_alpha<3>(Kf, al);
      else if (n==4) chol_alpha<4>(Kf, al);
      else chol_alpha<5>(Kf, al);
      for (int j=0;j<n;j++) sAlpha[j] = al[j];
    }
    __syncthreads();   // (I)
    float al[5];
    #pragma unroll
    for (int j=0;j<5;j++) al[j] = (j<n) ? sAlpha[j] : 0.f;
    float xn[24];
    #pragma unroll
    for (int c=0;c<24;c++) xn[c] = 0.f;
    #pragma unroll
    for (int j=0;j<5;j++){
      if (j < n){
        if (j == s){
          #pragma unroll
          for (int c=0;c<24;c++) xn[c] += al[j]*b2f(f2b(fv[c]));
        } else {
          float fv2[24];
          ld24c(g_F + (size_t)j*cBD, b, t, fv2);
          #pragma unroll
          for (int c=0;c<24;c++) xn[c] += al[j]*fv2[c];
        }
      }
    }
    st24c(g_X + (size_t)snext*cBD, b, t, xn);
  } else {
    // final iter: post-BN relu stats of stored F[4] (sFin region dead after (E))
    #pragma unroll
    for (int c=0;c<24;c++){
      float r = fmaxf(b2f(f2b(fv[c])), 0.f);
      float q2 = r*r;
      #pragma unroll
      for (int off=32;off;off>>=1){ r += __shfl_down(r,off,64); q2 += __shfl_down(q2,off,64); }
      if (lane==0){ sFin[wv*48+c*2]=r; sFin[wv*48+c*2+1]=q2; }
    }
    __syncthreads();
    if (t < 48){
      float vv = 0.f;
      #pragma unroll
      for (int w=0;w<16;w++) vv += sFin[w*48+t];
      atomicAdd(&g_stats2b[t], vv);
    }
  }
}

// ---- post: bn(relu(F[4])) + 8x8 avgpool + fc, one block per batch ----
__global__ void postfc_k(void* __restrict__ out){
  __shared__ float sPool[384];
  __shared__ float sMean[24], sRstd[24];
  int b = blockIdx.x, t = threadIdx.x;
  if (t < 24){
    const float inv = 1.f/(BB*HW);
    float mean = g_stats2b[t*2]*inv;
    float var = fmaxf(g_stats2b[t*2+1]*inv - mean*mean, 0.f);
    sMean[t] = mean; sRstd[t] = rsqrtf(var + 1e-5f);
  }
  __syncthreads();
  const ushortT* z = g_F + 4*cBD;
  for (int i=t; i<384; i+=256){
    int c = i>>4, bin = i&15, ph = bin>>2, pw = bin&3;
    int icv = c>>3, e = c&7;
    float gg = g_params[P_POG+c], bv = g_params[P_POB+c];
    float mean = sMean[c], rstd = sRstd[c];
    float sum = 0.f;
    for (int dy=0;dy<8;dy++)
      for (int dx=0;dx<8;dx++){
        int pix = (ph*8+dy)*32 + pw*8+dx;
        float vv = fmaxf(b2f(z[aidx(b,icv,pix) + e]), 0.f);
        sum += (vv-mean)*rstd*gg + bv;
      }
    sPool[i] = sum*(1.f/64.f);
  }
  __syncthreads();
  if (t < 10){
    float s2 = g_params[P_FCB+t];
    for (int k2=0;k2<384;k2++) s2 += sPool[k2]*g_params[P_FCW+t*384+k2];
    if (g_isbf16) ((bf16*)out)[b*10+t] = __float2bfloat16(s2);
    else ((float*)out)[b*10+t] = s2;
  }
}

extern "C" void kernel_launch(void* const* d_in, const int* in_sizes, int n_in,
                              void* d_out, int out_size, void* d_ws, size_t ws_size,
                              hipStream_t stream){
  const void* x   = d_in[0];
  const void* pcw = d_in[1];
  const void* pcb = d_in[2];
  const void* pbg = d_in[3];
  const void* pbb = d_in[4];
  const void* w1  = d_in[5];
  const void* g1g = d_in[6];
  const void* g1b = d_in[7];
  const void* w2  = d_in[8];
  const void* g2g = d_in[9];
  const void* g2b = d_in[10];
  const void* g3g = d_in[11];
  const void* g3b = d_in[12];
  const void* pog = d_in[13];
  const void* pob = d_in[14];
  const void* fcw = d_in[15];
  const void* fcb = d_in[16];
  (void)d_ws; (void)ws_size; (void)in_sizes; (void)n_in; (void)out_size;

  static bool attrSet = false;
  if (!attrSet){
    hipFuncSetAttribute(reinterpret_cast<const void*>(c2f_k),
                        hipFuncAttributeMaxDynamicSharedMemorySize, C2F_SMEM);
    attrSet = true;
  }

  detect_k<<<1,64,0,stream>>>(g1g);
  cvt_params_k<<<1,256,0,stream>>>(pcw,pcb,pbg,pbb,g1g,g1b,g2g,g2b,g3g,g3b,pog,pob,fcw,fcb);
  wtm_k<<<126,256,0,stream>>>(w1, w2);

  preconv_k<<<512,256,0,stream>>>(x);
  bn_apply_k<<<512,256,0,stream>>>();

  // k=0: conv1 on X0=0 is exactly zero -> yb=0, gn1sum=0 (zero0_k); skip conv1.
  zero0_k<<<4096,256,0,stream>>>();
  c2f_k<<<128,1024,C2F_SMEM,stream>>>(0, 1, 1);   // X[1] = F[0]

  for (int k=1;k<25;k++){
    int s = k%5;
    conv1_k<<<512,256,0,stream>>>(s);
    if (k < 24){
      int n = (k+1 < 5) ? (k+1) : 5;
      c2f_k<<<128,1024,C2F_SMEM,stream>>>(s, n, (k+1)%5);
    } else {
      c2f_k<<<128,1024,C2F_SMEM,stream>>>(s, 0, 0);  // final: F[4] + post stats
    }
  }

  postfc_k<<<128,256,0,stream>>>(d_out);
}

// Round 12
// 1358.580 us; speedup vs baseline: 1.0432x; 1.0432x over previous
//
#include <hip/hip_runtime.h>
#include <hip/hip_bf16.h>

typedef __hip_bfloat16 bf16;
typedef unsigned short ushortT;
typedef __attribute__((ext_vector_type(8))) short short8;
typedef __attribute__((ext_vector_type(4))) float f32x4;

#define BB 128
#define CHAN 24
#define INNER 64
#define HW 1024
#define DD (CHAN*HW)              // 24576

constexpr size_t cBD = (size_t)BB*DD;        // 3145728 elems
constexpr size_t cYB = (size_t)BB*INNER*HW;  // 8388608 elems

// ---------------- scratch in device globals ----------------
// aidx chunked bf16: [b][icv(3)][pix(1024)][8]  (c = icv*8+e)
__device__ __attribute__((aligned(16))) ushortT g_xp[cBD];
__device__ __attribute__((aligned(16))) ushortT g_X[5*cBD];
__device__ __attribute__((aligned(16))) ushortT g_F[5*cBD];
__device__ __attribute__((aligned(16))) ushortT g_G[5*cBD];
__device__ __attribute__((aligned(16))) ushortT g_yb[cYB];   // [b][pix][64]
__device__ __attribute__((aligned(16))) ushortT g_tb[cBD];   // preconv staging only
__device__ __attribute__((aligned(16))) ushortT g_w1m[9*64*32]; // bf16 [s][oc64][icp32]
__device__ __attribute__((aligned(16))) ushortT g_w2m[9*24*64]; // bf16 [s][oc24][ic64]
__device__ __attribute__((aligned(16))) float g_stats2a[48];
__device__ __attribute__((aligned(16))) float g_stats2b[48];
__device__ __attribute__((aligned(16))) float g_gn1sum[BB*8*2];
__device__ __attribute__((aligned(16))) float g_gram[BB*25];
__device__ __attribute__((aligned(16))) float g_params[5120];
__device__ unsigned g_isbf16;

#define P_PCW 0
#define P_PCB 648
#define P_PBG 672
#define P_PBB 696
#define P_G1G 720
#define P_G1B 784
#define P_G2G 848
#define P_G2B 872
#define P_G3G 896
#define P_G3B 920
#define P_POG 944
#define P_POB 968
#define P_FCW 992
#define P_FCB 4832

__device__ __forceinline__ size_t aidx(int b, int icv, int pix){
  return (((size_t)b*3 + icv)*1024 + (size_t)pix)*8;
}
__device__ __forceinline__ float rdin(const void* p, int i){
  if (g_isbf16) return __bfloat162float(((const bf16*)p)[i]);
  return ((const float*)p)[i];
}
__device__ __forceinline__ float b2f(ushortT u){
  unsigned v = ((unsigned)u) << 16;
  return __builtin_bit_cast(float, v);
}
__device__ __forceinline__ ushortT f2b(float f){
  unsigned u = __builtin_bit_cast(unsigned, f);
  u += 0x7FFFu + ((u >> 16) & 1u);   // RNE
  return (ushortT)(u >> 16);
}
__device__ __forceinline__ void ld24c(const ushortT* base, int b, int pix, float* o){
  #pragma unroll
  for (int icv=0;icv<3;icv++){
    short8 v = *(const short8*)&base[aidx(b,icv,pix)];
    #pragma unroll
    for (int j=0;j<8;j++) o[icv*8+j] = b2f((ushortT)v[j]);
  }
}
__device__ __forceinline__ void st24c(ushortT* base, int b, int pix, const float* i){
  #pragma unroll
  for (int icv=0;icv<3;icv++){
    short8 v;
    #pragma unroll
    for (int j=0;j<8;j++) v[j] = (short)f2b(i[icv*8+j]);
    *(short8*)&base[aidx(b,icv,pix)] = v;
  }
}

// ---- dtype detector ----
__global__ void detect_k(const void* g1g){
  if (threadIdx.x==0 && blockIdx.x==0){
    unsigned u = *(const unsigned*)g1g;
    g_isbf16 = (u == 0x3F803F80u) ? 1u : 0u;
  }
}

// ---- convert params to fp32; zero BN sum buffers ----
__global__ void cvt_params_k(const void* pcw, const void* pcb, const void* pbg, const void* pbb,
                             const void* g1g, const void* g1b, const void* g2g, const void* g2b,
                             const void* g3g, const void* g3b, const void* pog, const void* pob,
                             const void* fcw, const void* fcb){
  int t = threadIdx.x;
  for (int i=t;i<648;i+=256)  g_params[P_PCW+i]=rdin(pcw,i);
  for (int i=t;i<24;i+=256) { g_params[P_PCB+i]=rdin(pcb,i);
                              g_params[P_PBG+i]=rdin(pbg,i);
                              g_params[P_PBB+i]=rdin(pbb,i);
                              g_params[P_G2G+i]=rdin(g2g,i);
                              g_params[P_G2B+i]=rdin(g2b,i);
                              g_params[P_G3G+i]=rdin(g3g,i);
                              g_params[P_G3B+i]=rdin(g3b,i);
                              g_params[P_POG+i]=rdin(pog,i);
                              g_params[P_POB+i]=rdin(pob,i); }
  for (int i=t;i<64;i+=256) { g_params[P_G1G+i]=rdin(g1g,i);
                              g_params[P_G1B+i]=rdin(g1b,i); }
  for (int i=t;i<3840;i+=256) g_params[P_FCW+i]=rdin(fcw,i);
  for (int i=t;i<10;i+=256)   g_params[P_FCB+i]=rdin(fcb,i);
  for (int i=t;i<48;i+=256) { g_stats2a[i]=0.f; g_stats2b[i]=0.f; }
}

// ---- weight pack to bf16 MFMA layouts ----
__global__ void wtm_k(const void* w1, const void* w2){
  int t = blockIdx.x*256 + threadIdx.x;
  if (t < 9*64*32){
    int ic = t & 31, oc = (t>>5)&63, s9 = t>>11;
    float v = (ic<24) ? rdin(w1, (oc*24+ic)*9 + s9) : 0.f;
    g_w1m[t] = f2b(v);
  }
  int u = t - 9*64*32;
  if (u >= 0 && u < 9*24*64){
    int ic = u & 63; int rest = u >> 6; int oc = rest % 24; int s9 = rest / 24;
    g_w2m[u] = f2b(rdin(w2, (oc*64+ic)*9 + s9));
  }
}

// grid 4096: zero yb, X0, gn1sum
__global__ void zero0_k(){
  size_t base = ((size_t)blockIdx.x*256 + threadIdx.x)*8;
  short8 z = {0,0,0,0,0,0,0,0};
  *(short8*)&g_yb[base] = z;
  if (blockIdx.x < 1536) *(short8*)&g_X[base] = z;
  int t = blockIdx.x*256 + threadIdx.x;
  if (blockIdx.x < 8)  g_gn1sum[t] = 0.f;
}

// ---- pre conv -> g_tb (aidx) + pre-BN stats (fused) ----
__global__ void preconv_k(const void* __restrict__ x){
  __shared__ float sR2d[4*48];
  int id = blockIdx.x*256 + threadIdx.x;   // pixel id 0..131071
  int b = id >> 10, pix = id & 1023;
  int yy = pix >> 5, xx = pix & 31;
  float acc[24];
  #pragma unroll
  for (int oc=0;oc<24;oc++) acc[oc] = g_params[P_PCB+oc];
  for (int ic=0; ic<3; ic++)
    for (int ky=0; ky<3; ky++){
      int gy = yy+ky-1; if (gy<0||gy>=32) continue;
      for (int kx=0;kx<3;kx++){
        int gx = xx+kx-1; if (gx<0||gx>=32) continue;
        float v = rdin(x, ((b*3+ic)*32+gy)*32+gx);
        #pragma unroll
        for (int oc=0;oc<24;oc++)
          acc[oc] += v * g_params[P_PCW+(oc*3+ic)*9+ky*3+kx];
      }
    }
  st24c(g_tb, b, pix, acc);
  int lane = threadIdx.x & 63, wv = threadIdx.x >> 6;
  #pragma unroll
  for (int c=0;c<24;c++){
    float r = acc[c], q = acc[c]*acc[c];
    #pragma unroll
    for (int off=32;off;off>>=1){ r += __shfl_down(r,off,64); q += __shfl_down(q,off,64); }
    if (lane==0){ sR2d[wv*48+c*2]=r; sR2d[wv*48+c*2+1]=q; }
  }
  __syncthreads();
  if (threadIdx.x < 48)
    atomicAdd(&g_stats2a[threadIdx.x],
      sR2d[threadIdx.x] + sR2d[48+threadIdx.x] + sR2d[96+threadIdx.x] + sR2d[144+threadIdx.x]);
}

// ---- bn apply: tb -> xp (both aidx) ----
__global__ void bn_apply_k(){
  int id = blockIdx.x*256+threadIdx.x;   // pixel
  int b = id >> 10, pix = id & 1023;
  const float inv = 1.f/(BB*HW);
  float tv[24], ov[24];
  ld24c(g_tb, b, pix, tv);
  #pragma unroll
  for (int c=0;c<24;c++){
    float mean = g_stats2a[c*2]*inv;
    float var = fmaxf(g_stats2a[c*2+1]*inv - mean*mean, 0.f);
    float rstd = rsqrtf(var + 1e-5f);
    ov[c] = (tv[c]-mean)*rstd*g_params[P_PBG+c] + g_params[P_PBB+c];
  }
  st24c(g_xp, b, pix, ov);
}

// ============ conv1 MFMA (r10 verbatim, XCD-aligned block decode): X[s] -> yb + GN1 ============
__launch_bounds__(256, 2)
__global__ void conv1_k(int s){
  __shared__ ushortT sMem[29312];   // sA 10880 | sW 18432 ; reused as sOut(16384)
  ushortT* sA = sMem;
  ushortT* sW = sMem + 10880;
  const int tid = threadIdx.x;
  const int lane = tid & 63, wv = tid >> 6;
  const int mLane = lane & 15, q = lane >> 4;
  const int bid = blockIdx.x;
  const int b = (bid & 7) + ((bid >> 5) << 3);
  const int yt = (bid >> 3) & 3;
  const ushortT* __restrict__ Xs = g_X + (size_t)s*cBD;
  for (int i = tid; i < 1360; i += 256){
    int icv = i & 3, apix = i >> 2;
    int yl = apix / 34, xl = apix - yl*34;
    int gy = yt*8 - 1 + yl, gx = xl - 1;
    short8 v = {0,0,0,0,0,0,0,0};
    if (gy >= 0 && gy < 32 && gx >= 0 && gx < 32 && icv < 3)
      v = *(const short8*)&Xs[aidx(b, icv, gy*32 + gx)];
    *(short8*)&sA[(size_t)(apix*4 + (icv ^ (apix&3)))*8] = v;
  }
  for (int i = tid; i < 2304; i += 256){
    int icv = i & 3, rest = i >> 2;
    int oc = rest & 63, s9 = rest >> 6;
    short8 v = *(const short8*)&g_w1m[(size_t)((s9*64 + oc)*32) + icv*8];
    *(short8*)&sW[(size_t)((s9*64+oc)*4 + (icv ^ (oc&3)))*8] = v;
  }
  __syncthreads();
  f32x4 acc[4][4];
  #pragma unroll
  for (int mt=0;mt<4;mt++)
    #pragma unroll
    for (int nt=0;nt<4;nt++) acc[mt][nt] = (f32x4){0.f,0.f,0.f,0.f};
  for (int s9=0; s9<9; s9++){
    int ky = s9/3, kx = s9 - ky*3;
    short8 bfr[4];
    #pragma unroll
    for (int nt=0;nt<4;nt++){
      int oc = nt*16 + mLane;
      bfr[nt] = *(const short8*)&sW[(size_t)((s9*64+oc)*4 + (q ^ (oc&3)))*8];
    }
    #pragma unroll
    for (int mt=0;mt<4;mt++){
      int g = wv*4+mt;
      int apix = ((g>>1) + ky)*34 + (g&1)*16 + mLane + kx;
      short8 afr = *(const short8*)&sA[(size_t)(apix*4 + (q ^ (apix&3)))*8];
      #pragma unroll
      for (int nt=0;nt<4;nt++)
        acc[mt][nt] = __builtin_amdgcn_mfma_f32_16x16x32_bf16(afr, bfr[nt], acc[mt][nt], 0,0,0);
    }
  }
  __syncthreads();
  ushortT* sOut = sMem;
  #pragma unroll
  for (int mt=0;mt<4;mt++){
    int g = wv*4+mt;
    #pragma unroll
    for (int nt=0;nt<4;nt++){
      int oc = nt*16 + mLane;
      #pragma unroll
      for (int r=0;r<4;r++){
        int pix = (g>>1)*32 + (g&1)*16 + q*4 + r;
        sOut[pix*64 + oc] = f2b(fmaxf(acc[mt][nt][r], 0.f));
      }
    }
  }
  __syncthreads();
  float s0=0.f, s1=0.f;
  size_t gbase = ((size_t)b*1024 + yt*256)*64;
  for (int c = tid; c < 2048; c += 256){
    short8 v = *(const short8*)&sOut[c*8];
    *(short8*)&g_yb[gbase + (size_t)c*8] = v;
    #pragma unroll
    for (int j=0;j<8;j++){ float f = b2f((ushortT)v[j]); s0 += f; s1 += f*f; }
  }
  s0 += __shfl_down(s0,32); s1 += __shfl_down(s1,32);
  s0 += __shfl_down(s0,16); s1 += __shfl_down(s1,16);
  s0 += __shfl_down(s0, 8); s1 += __shfl_down(s1, 8);
  if (lane < 8){
    atomicAdd(&g_gn1sum[(b*8+lane)*2],   s0);
    atomicAdd(&g_gn1sum[(b*8+lane)*2+1], s1);
  }
}

// ---- Cholesky solve for Anderson alpha ----
template<int N>
__device__ __forceinline__ void chol_alpha(const float Kf[5][5], float* alpha){
  double K[N][N];
  #pragma unroll
  for (int i=0;i<N;i++)
    #pragma unroll
    for (int j=0;j<N;j++)
      K[i][j] = (double)Kf[i][j] + (i==j ? 1e-4 : 0.0);
  #pragma unroll
  for (int c=0;c<N;c++){
    double d = K[c][c];
    #pragma unroll
    for (int k2=0;k2<c;k2++) d -= K[c][k2]*K[c][k2];
    d = sqrt(fmax(d, 1e-300));
    K[c][c] = d;
    double inv = 1.0/d;
    #pragma unroll
    for (int r=c+1;r<N;r++){
      double v = K[r][c];
      #pragma unroll
      for (int k2=0;k2<c;k2++) v -= K[r][k2]*K[c][k2];
      K[r][c] = v*inv;
    }
  }
  double y[N];
  #pragma unroll
  for (int i=0;i<N;i++){
    double v = 1.0;
    #pragma unroll
    for (int j=0;j<i;j++) v -= K[i][j]*y[j];
    y[i] = v / K[i][i];
  }
  double w[N];
  #pragma unroll
  for (int i=N-1;i>=0;i--){
    double v = y[i];
    #pragma unroll
    for (int j=i+1;j<N;j++) v -= K[j][i]*w[j];
    w[i] = v / K[i][i];
  }
  double sum = 0.0;
  #pragma unroll
  for (int i=0;i<N;i++) sum += w[i];
  double invs = 1.0/sum;
  #pragma unroll
  for (int i=0;i<N;i++) alpha[i] = (float)(w[i]*invs);
}

// ====== c2f_k: conv2 (whole image, MFMA) + round-1 fuse, one block/batch ======
// 128 blocks x 1024 threads. LDS (ushort offsets):
//   [0,65536)      sYb: [pix][8 slot=chk^(pix&7)][8]   (128 KB)
//                  sTB alias after conv2: [pix][4 slot=icv^((pix>>2)&3)][8] (64 KB)
//   [65536,79360)  sW2: [s9][oc][8 slot=icv^(oc&7)][8] (27 KB)
//   floats after:  680 floats
// LDS caps occupancy at 1 block/CU (4 waves/SIMD); lift the 64-VGPR budget so
// the software-pipelined staging loads stay in registers (r11's spill lesson).
#define C2F_SMEM 161440

__attribute__((amdgpu_flat_work_group_size(1024,1024), amdgpu_waves_per_eu(1)))
__global__ void c2f_k(int s, int n, int snext){
  extern __shared__ __align__(16) ushortT sU[];
  ushortT* sYb = sU;
  ushortT* sTB = sU;
  ushortT* sW2 = sU + 65536;
  float* sS    = (float*)(sU + 79360);
  float* sAff1  = sS;         // 128
  float* sStat2 = sS + 128;   // 48
  float* sAff2  = sS + 176;   // 48
  float* sStat3 = sS + 224;   // 16 (m,rstd per group)
  float* sAff3  = sS + 240;   // 48
  float* sRed   = sS + 288;   // 256 (16 waves x 8grp x {S,Q})
  float* sRedG  = sS + 544;   // 80
  float* sAlpha = sS + 624;   // 8
  float* sFin   = (float*)sTB; // fin-only scratch (region dead by then)

  const int b = blockIdx.x;
  const int t = threadIdx.x;
  const int lane = t & 63, wv = t >> 6;
  const int mLane = lane & 15, q = lane >> 4;
  const int g0 = wv*4;
  const bool ntOK = (mLane < 8);
  const bool fin = (n == 0);

  // GN1 affine from conv1's global sums, then zero them for next iter
  if (t < 64){
    const int c = t, gr = c>>3;
    float S = g_gn1sum[(b*8+gr)*2], Q = g_gn1sum[(b*8+gr)*2+1];
    float mean = S*(1.f/8192.f);
    float var  = fmaxf(Q*(1.f/8192.f) - mean*mean, 0.f);
    float rstd = rsqrtf(var + 1e-5f);
    float sc = rstd*g_params[P_G1G+c];
    sAff1[c] = sc; sAff1[64+c] = g_params[P_G1B+c] - mean*sc;
  }
  if (t < 16) g_gn1sum[b*16 + t] = 0.f;   // same wave, after reads
  if (t >= 64 && t < 112) sStat2[t-64] = 0.f;
  if (t >= 112 && t < 128) sStat3[t-112] = 0.f;
  __syncthreads();   // (A) sAff1 ready

  // stage yb (GN1 applied, bf16-rounded) + w2 into swizzled LDS.
  // Software-pipelined: issue all 8 global loads first (8x MLP), then convert.
  {
    short8 raw[8];
    #pragma unroll
    for (int it=0; it<8; ++it){
      int i = t + it*1024;
      int chk = i & 7, pix = i >> 3;
      raw[it] = *(const short8*)&g_yb[((size_t)b*1024 + pix)*64 + chk*8];
    }
    #pragma unroll
    for (int it=0; it<8; ++it){
      int i = t + it*1024;
      int chk = i & 7, pix = i >> 3;
      short8 v;
      #pragma unroll
      for (int j=0;j<8;j++){
        int c = chk*8+j;
        v[j] = (short)f2b(b2f((ushortT)raw[it][j])*sAff1[c] + sAff1[64+c]);
      }
      *(short8*)&sYb[(size_t)(pix*8 + (chk^(pix&7)))*8] = v;
    }
  }
  for (int i=t; i<1728; i+=1024){
    int icv=i&7, rest=i>>3, oc=rest%24, s9=rest/24;
    *(short8*)&sW2[(size_t)((s9*24+oc)*8 + (icv^(oc&7)))*8] =
      *(const short8*)&g_w2m[(size_t)((s9*24+oc)*64) + icv*8];
  }
  __syncthreads();   // (B) yb, w2 ready

  // ---------------- conv2 MFMA: whole image, wave -> 64 pixels ----------------
  f32x4 a2[4][2];
  #pragma unroll
  for (int mt=0;mt<4;mt++){ a2[mt][0]=(f32x4){0.f,0.f,0.f,0.f}; a2[mt][1]=(f32x4){0.f,0.f,0.f,0.f}; }
  for (int s9=0; s9<9; ++s9){
    const int ky = s9/3, kx = s9 - ky*3;
    #pragma unroll
    for (int ks=0; ks<2; ++ks){
      const int ch = ks*4 + q;
      short8 b0 = *(const short8*)&sW2[(size_t)((s9*24+mLane)*8 + (ch^(mLane&7)))*8];
      short8 b1 = ntOK ? *(const short8*)&sW2[(size_t)((s9*24+16+mLane)*8 + (ch^(mLane&7)))*8]
                       : (short8){0,0,0,0,0,0,0,0};
      #pragma unroll
      for (int mt=0;mt<4;mt++){
        const int g = g0+mt;
        const int gy = (g>>1) + ky - 1;
        const int gx = (g&1)*16 + mLane + kx - 1;
        short8 afr = {0,0,0,0,0,0,0,0};
        if (gy>=0 && gy<32 && gx>=0 && gx<32){
          const int pp = gy*32 + gx;
          afr = *(const short8*)&sYb[(size_t)(pp*8 + (ch^(pp&7)))*8];
        }
        a2[mt][0] = __builtin_amdgcn_mfma_f32_16x16x32_bf16(afr, b0, a2[mt][0], 0,0,0);
        a2[mt][1] = __builtin_amdgcn_mfma_f32_16x16x32_bf16(afr, b1, a2[mt][1], 0,0,0);
      }
    }
  }
  // v = a2 + xp (scalar aidx reads, round-1 pattern) ; GN2 stats (unrounded)
  #pragma unroll
  for (int ci=0; ci<2; ++ci){
    const int oc = ci*16 + mLane;
    const bool ok = (ci==0) || ntOK;
    const int icv = oc>>3, e = oc&7;
    float s0=0.f, s1=0.f;
    if (ok){
      #pragma unroll
      for (int mt=0;mt<4;mt++){
        #pragma unroll
        for (int r=0;r<4;r++){
          const int pp = (g0+mt)*16 + q*4 + r;
          float v = a2[mt][ci][r] + b2f(g_xp[aidx(b,icv,pp)+e]);
          a2[mt][ci][r] = v;
          s0 += v; s1 += v*v;
        }
      }
    }
    s0 += __shfl_down(s0,32); s1 += __shfl_down(s1,32);
    s0 += __shfl_down(s0,16); s1 += __shfl_down(s1,16);
    if (lane < 16 && ok){
      atomicAdd(&sStat2[oc*2],   s0);
      atomicAdd(&sStat2[oc*2+1], s1);
    }
  }
  __syncthreads();   // (C) all sYb reads + stats2 done -> region reusable

  // handoff tb' = f2b(v) into sTB (dead yb region)
  #pragma unroll
  for (int ci=0; ci<2; ++ci){
    const int oc = ci*16 + mLane;
    if ((ci==0) || ntOK){
      const int icv = oc>>3, e = oc&7;
      #pragma unroll
      for (int mt=0;mt<4;mt++)
        #pragma unroll
        for (int r=0;r<4;r++){
          const int pp = (g0+mt)*16 + q*4 + r;
          sTB[(size_t)(pp*4 + (icv ^ ((pp>>2)&3)))*8 + e] = f2b(a2[mt][ci][r]);
        }
    }
  }
  if (t < 24){
    const int gr = t/3;
    float S = sStat2[(gr*3)*2]  +sStat2[(gr*3+1)*2]  +sStat2[(gr*3+2)*2];
    float Q = sStat2[(gr*3)*2+1]+sStat2[(gr*3+1)*2+1]+sStat2[(gr*3+2)*2+1];
    float m = S*(1.f/3072.f);
    float rstd = rsqrtf(fmaxf(Q*(1.f/3072.f)-m*m,0.f)+1e-5f);
    float sc = rstd*g_params[P_G2G+t];
    sAff2[t] = sc; sAff2[24+t] = g_params[P_G2B+t] - m*sc;
  }
  __syncthreads();   // (D) handoff + aff2 ready

  // ---------------- pixel phase (round-1 fuse_k verbatim; t = pixel) ----------------
  float v[24], xv[24];
  #pragma unroll
  for (int i=0;i<3;i++){
    short8 t8 = *(const short8*)&sTB[(size_t)(t*4 + (i ^ ((t>>2)&3)))*8];
    #pragma unroll
    for (int j8=0;j8<8;j8++) v[i*8+j8] = b2f((ushortT)t8[j8]);
  }
  ld24c(g_X + (size_t)s*cBD, b, t, xv);
  float p0[8], p1[8];
  #pragma unroll
  for (int g=0;g<8;g++){ p0[g]=0.f; p1[g]=0.f; }
  #pragma unroll
  for (int c=0;c<24;c++){
    float val = fmaxf(xv[c] + v[c]*sAff2[c] + sAff2[24+c], 0.f);
    v[c] = val;
    int g = c/3;
    p0[g] += val; p1[g] += val*val;
  }
  #pragma unroll
  for (int g=0;g<8;g++){
    #pragma unroll
    for (int off=32;off;off>>=1){ p0[g]+=__shfl_down(p0[g],off,64); p1[g]+=__shfl_down(p1[g],off,64); }
  }
  if (lane==0){
    #pragma unroll
    for (int g=0;g<8;g++){ sRed[wv*16+g*2]=p0[g]; sRed[wv*16+g*2+1]=p1[g]; }
  }
  __syncthreads();   // (E) -- sTB reads also all done
  if (t < 8){
    float S=0.f, Q=0.f;
    #pragma unroll
    for (int w=0;w<16;w++){ S += sRed[w*16+t*2]; Q += sRed[w*16+t*2+1]; }
    float m = S*(1.f/3072.f);
    sStat3[t*2]   = m;
    sStat3[t*2+1] = rsqrtf(fmaxf(Q*(1.f/3072.f) - m*m, 0.f) + 1e-5f);
  }
  __syncthreads();   // (F)
  if (t < 24){
    int g = t/3;
    float sc = sStat3[g*2+1]*g_params[P_G3G+t];
    sAff3[t] = sc; sAff3[24+t] = g_params[P_G3B+t] - sStat3[g*2]*sc;
  }
  __syncthreads();   // (G)
  float fv[24];
  #pragma unroll
  for (int c=0;c<24;c++) fv[c] = v[c]*sAff3[c] + sAff3[24+c];
  st24c(g_F + (size_t)s*cBD, b, t, fv);

  if (!fin){
    float gl[24];
    #pragma unroll
    for (int c=0;c<24;c++) gl[c] = b2f(f2b(fv[c] - xv[c]));   // bf16-rounded residual
    st24c(g_G + (size_t)s*cBD, b, t, gl);
    float part[5];
    #pragma unroll
    for (int j=0;j<5;j++) part[j]=0.f;
    #pragma unroll
    for (int j=0;j<5;j++){
      if (j < n){
        float acc=0.f;
        if (j == s){
          #pragma unroll
          for (int c=0;c<24;c++) acc += gl[c]*gl[c];
        } else {
          float gv[24];
          ld24c(g_G + (size_t)j*cBD, b, t, gv);
          #pragma unroll
          for (int c=0;c<24;c++) acc += gl[c]*gv[c];
        }
        part[j] = acc;
      }
    }
    #pragma unroll
    for (int j=0;j<5;j++){
      float vv = part[j];
      #pragma unroll
      for (int off=32;off;off>>=1) vv += __shfl_down(vv,off,64);
      if (lane==0) sRedG[wv*5+j] = vv;
    }
    __syncthreads();   // (H)
    if (t == 0){
      for (int j=0;j<n;j++){
        float vv = 0.f;
        for (int w=0;w<16;w++) vv += sRedG[w*5+j];
        g_gram[b*25+s*5+j] = vv;
        g_gram[b*25+j*5+s] = vv;
      }
      float Kf[5][5];
      for (int i=0;i<n;i++)
        for (int j=0;j<n;j++) Kf[i][j] = g_gram[b*25+i*5+j];
      float al[5];
      if (n==1) al[0]=1.f;
      else if (n==2) chol_alpha<2>(Kf, al);
      else if (n==3) chol_alpha<3>(Kf, al);
      else if (n==4) chol_alpha<4>(Kf, al);
      else chol_alpha<5>(Kf, al);
      for (int j=0;j<n;j++) sAlpha[j] = al[j];
    }
    __syncthreads();   // (I)
    float al[5];
    #pragma unroll
    for (int j=0;j<5;j++) al[j] = (j<n) ? sAlpha[j] : 0.f;
    float xn[24];
    #pragma unroll
    for (int c=0;c<24;c++) xn[c] = 0.f;
    #pragma unroll
    for (int j=0;j<5;j++){
      if (j < n){
        if (j == s){
          #pragma unroll
          for (int c=0;c<24;c++) xn[c] += al[j]*b2f(f2b(fv[c]));
        } else {
          float fv2[24];
          ld24c(g_F + (size_t)j*cBD, b, t, fv2);
          #pragma unroll
          for (int c=0;c<24;c++) xn[c] += al[j]*fv2[c];
        }
      }
    }
    st24c(g_X + (size_t)snext*cBD, b, t, xn);
  } else {
    // final iter: post-BN relu stats of stored F[4] (sFin region dead after (E))
    #pragma unroll
    for (int c=0;c<24;c++){
      float r = fmaxf(b2f(f2b(fv[c])), 0.f);
      float q2 = r*r;
      #pragma unroll
      for (int off=32;off;off>>=1){ r += __shfl_down(r,off,64); q2 += __shfl_down(q2,off,64); }
      if (lane==0){ sFin[wv*48+c*2]=r; sFin[wv*48+c*2+1]=q2; }
    }
    __syncthreads();
    if (t < 48){
      float vv = 0.f;
      #pragma unroll
      for (int w=0;w<16;w++) vv += sFin[w*48+t];
      atomicAdd(&g_stats2b[t], vv);
    }
  }
}

// ---- post: bn(relu(F[4])) + 8x8 avgpool + fc, one block per batch ----
__global__ void postfc_k(void* __restrict__ out){
  __shared__ float sPool[384];
  __shared__ float sMean[24], sRstd[24];
  int b = blockIdx.x, t = threadIdx.x;
  if (t < 24){
    const float inv = 1.f/(BB*HW);
    float mean = g_stats2b[t*2]*inv;
    float var = fmaxf(g_stats2b[t*2+1]*inv - mean*mean, 0.f);
    sMean[t] = mean; sRstd[t] = rsqrtf(var + 1e-5f);
  }
  __syncthreads();
  const ushortT* z = g_F + 4*cBD;
  for (int i=t; i<384; i+=256){
    int c = i>>4, bin = i&15, ph = bin>>2, pw = bin&3;
    int icv = c>>3, e = c&7;
    float gg = g_params[P_POG+c], bv = g_params[P_POB+c];
    float mean = sMean[c], rstd = sRstd[c];
    float sum = 0.f;
    for (int dy=0;dy<8;dy++)
      for (int dx=0;dx<8;dx++){
        int pix = (ph*8+dy)*32 + pw*8+dx;
        float vv = fmaxf(b2f(z[aidx(b,icv,pix) + e]), 0.f);
        sum += (vv-mean)*rstd*gg + bv;
      }
    sPool[i] = sum*(1.f/64.f);
  }
  __syncthreads();
  if (t < 10){
    float s2 = g_params[P_FCB+t];
    for (int k2=0;k2<384;k2++) s2 += sPool[k2]*g_params[P_FCW+t*384+k2];
    if (g_isbf16) ((bf16*)out)[b*10+t] = __float2bfloat16(s2);
    else ((float*)out)[b*10+t] = s2;
  }
}

extern "C" void kernel_launch(void* const* d_in, const int* in_sizes, int n_in,
                              void* d_out, int out_size, void* d_ws, size_t ws_size,
                              hipStream_t stream){
  const void* x   = d_in[0];
  const void* pcw = d_in[1];
  const void* pcb = d_in[2];
  const void* pbg = d_in[3];
  const void* pbb = d_in[4];
  const void* w1  = d_in[5];
  const void* g1g = d_in[6];
  const void* g1b = d_in[7];
  const void* w2  = d_in[8];
  const void* g2g = d_in[9];
  const void* g2b = d_in[10];
  const void* g3g = d_in[11];
  const void* g3b = d_in[12];
  const void* pog = d_in[13];
  const void* pob = d_in[14];
  const void* fcw = d_in[15];
  const void* fcb = d_in[16];
  (void)d_ws; (void)ws_size; (void)in_sizes; (void)n_in; (void)out_size;

  static bool attrSet = false;
  if (!attrSet){
    hipFuncSetAttribute(reinterpret_cast<const void*>(c2f_k),
                        hipFuncAttributeMaxDynamicSharedMemorySize, C2F_SMEM);
    attrSet = true;
  }

  detect_k<<<1,64,0,stream>>>(g1g);
  cvt_params_k<<<1,256,0,stream>>>(pcw,pcb,pbg,pbb,g1g,g1b,g2g,g2b,g3g,g3b,pog,pob,fcw,fcb);
  wtm_k<<<126,256,0,stream>>>(w1, w2);

  preconv_k<<<512,256,0,stream>>>(x);
  bn_apply_k<<<512,256,0,stream>>>();

  // k=0: conv1 on X0=0 is exactly zero -> yb=0, gn1sum=0 (zero0_k); skip conv1.
  zero0_k<<<4096,256,0,stream>>>();
  c2f_k<<<128,1024,C2F_SMEM,stream>>>(0, 1, 1);   // X[1] = F[0]

  for (int k=1;k<25;k++){
    int s = k%5;
    conv1_k<<<512,256,0,stream>>>(s);
    if (k < 24){
      int n = (k+1 < 5) ? (k+1) : 5;
      c2f_k<<<128,1024,C2F_SMEM,stream>>>(s, n, (k+1)%5);
    } else {
      c2f_k<<<128,1024,C2F_SMEM,stream>>>(s, 0, 0);  // final: F[4] + post stats
    }
  }

  postfc_k<<<128,256,0,stream>>>(d_out);
}